// Round 13
// baseline (251.786 us; speedup 1.0000x reference)
//
#include <hip/hip_runtime.h>
#include <hip/hip_fp16.h>
#include <cstdint>
#include <cstddef>

#define NNODES 100000
#define NEDGES 1600000
#define NGRAPHS 64
#define BSHIFT 7
#define BRANGE 128
#define NB 782  // ceil(NNODES / 128)
#define NZ (NB + 2)  // bcnt + done counters
#define POOLCH 32    // chunks per graph

typedef short short8v __attribute__((ext_vector_type(8)));
typedef float float4v __attribute__((ext_vector_type(4)));

__device__ inline short f2h_s(float f) {
    __half h = __float2half(f);
    return __builtin_bit_cast(short, h);
}
__device__ inline ushort f2h_u(float f) {
    __half h = __float2half(f);
    return __builtin_bit_cast(ushort, h);
}
__device__ inline __half2 u2h2(uint u) { return __builtin_bit_cast(__half2, u); }
__device__ inline uint h22u(__half2 h) { return __builtin_bit_cast(uint, h); }

// ---------------- setup: zero ∪ prepw ∪ bounds (block-range partitioned) ----------------
// blocks 0..3: zero NZ ints. blocks 4,5: W1/W2 -> fragment-ordered fp16. blocks 6..396: bounds.

__global__ __launch_bounds__(256) void k_setup(int* __restrict__ zb,
                                               const float* __restrict__ W1,
                                               const float* __restrict__ W2,
                                               short8v* __restrict__ o1,
                                               short8v* __restrict__ o2,
                                               const int* __restrict__ batch,
                                               int* __restrict__ gstart,
                                               int* __restrict__ gend) {
    int b = blockIdx.x, t = threadIdx.x;
    if (b < 4) {
        int i = b * 256 + t;
        if (i < NZ) zb[i] = 0;
    } else if (b < 6) {
        const float* W = (b == 5) ? W2 : W1;
        short8v* o = (b == 5) ? o2 : o1;
        for (int s = t; s < 2048; s += 256) {
            int p = s >> 6, l = s & 63;
            int kb = (p >> 3) * 32 + ((l >> 4) * 8);
            int j = (p & 7) * 16 + (l & 15);
            short8v v;
            #pragma unroll
            for (int i = 0; i < 8; ++i)
                v[i] = f2h_s(W[(size_t)(kb + i) * 128 + j]);
            o[s] = v;
        }
    } else {
        int i = (b - 6) * 256 + t;
        if (i < NNODES) {
            int bb = batch[i];
            if (i == 0 || batch[i - 1] != bb) gstart[bb] = i;
            if (i == NNODES - 1 || batch[i + 1] != bb) gend[bb] = i + 1;
        }
    }
}

// ---------------- bucket count + fused last-block scan ----------------

__global__ __launch_bounds__(256) void k_bcount_scan(const int* __restrict__ dst,
                                                     int* __restrict__ bcnt,
                                                     int* __restrict__ boffs,
                                                     int* __restrict__ bcur,
                                                     int* __restrict__ done, int E) {
    __shared__ int h[NB];
    __shared__ int ticket;
    int t = threadIdx.x;
    for (int i = t; i < NB; i += 256) h[i] = 0;
    __syncthreads();
    for (int e = blockIdx.x * 256 + t; e < E; e += gridDim.x * 256)
        atomicAdd(&h[dst[e] >> BSHIFT], 1);
    __syncthreads();
    for (int i = t; i < NB; i += 256)
        if (h[i]) atomicAdd(&bcnt[i], h[i]);
    __threadfence();
    if (t == 0) ticket = atomicAdd(done, 1);
    __syncthreads();
    if (ticket != gridDim.x - 1) return;
    // last block: exclusive scan of bcnt[0..NB) -> boffs, bcur
    __threadfence();
    int base = t * 4;
    int v0 = base + 0 < NB ? atomicAdd(&bcnt[base + 0], 0) : 0;
    int v1 = base + 1 < NB ? atomicAdd(&bcnt[base + 1], 0) : 0;
    int v2 = base + 2 < NB ? atomicAdd(&bcnt[base + 2], 0) : 0;
    int v3 = base + 3 < NB ? atomicAdd(&bcnt[base + 3], 0) : 0;
    int tsum = v0 + v1 + v2 + v3;
    __syncthreads();
    h[t] = tsum;
    __syncthreads();
    #pragma unroll
    for (int d = 1; d < 256; d <<= 1) {
        int val = (t >= d) ? h[t - d] : 0;
        __syncthreads();
        h[t] += val;
        __syncthreads();
    }
    int excl = h[t] - tsum;
    if (base + 0 < NB) { boffs[base + 0] = excl;                bcur[base + 0] = excl; }
    if (base + 1 < NB) { boffs[base + 1] = excl + v0;           bcur[base + 1] = excl + v0; }
    if (base + 2 < NB) { boffs[base + 2] = excl + v0 + v1;      bcur[base + 2] = excl + v0 + v1; }
    if (base + 3 < NB) { boffs[base + 3] = excl + v0 + v1 + v2; bcur[base + 3] = excl + v0 + v1 + v2; }
    if (t == 0) boffs[NB] = E;
}

// P1: scatter packed (src | (dst&127)<<24) into bucket-grouped order.
#define P1_EPT 8
__global__ __launch_bounds__(256) void k_bscatter(const int* __restrict__ src,
                                                  const int* __restrict__ dst,
                                                  int* __restrict__ bcur,
                                                  uint* __restrict__ pairs, int E) {
    __shared__ int h[NB];
    __shared__ int base[NB];
    int t = threadIdx.x;
    long long c0 = (long long)blockIdx.x * 2048;
    if (c0 >= E) return;
    for (int i = t; i < NB; i += 256) h[i] = 0;
    __syncthreads();
    int myb[P1_EPT], mylp[P1_EPT];
    uint myv[P1_EPT];
    #pragma unroll
    for (int k = 0; k < P1_EPT; ++k) {
        long long e = c0 + t + k * 256;
        if (e < E) {
            int d = dst[e];
            myv[k] = (uint)src[e] | ((uint)(d & (BRANGE - 1)) << 24);
            myb[k] = d >> BSHIFT;
            mylp[k] = atomicAdd(&h[myb[k]], 1);
        } else myb[k] = -1;
    }
    __syncthreads();
    for (int i = t; i < NB; i += 256)
        base[i] = h[i] ? atomicAdd(&bcur[i], h[i]) : 0;
    __syncthreads();
    #pragma unroll
    for (int k = 0; k < P1_EPT; ++k)
        if (myb[k] >= 0) pairs[base[myb[k]] + mylp[k]] = myv[k];
}

// Fused per-bucket: node histogram -> dinv + offs (boffs[b] + local scan) -> CSR scatter
__global__ __launch_bounds__(256) void k_build(const uint* __restrict__ pairs,
                                               const int* __restrict__ boffs,
                                               int* __restrict__ offs,
                                               float* __restrict__ dinv,
                                               int* __restrict__ csr, int N) {
    __shared__ int h[256];
    __shared__ int sh[256];
    __shared__ int cur[BRANGE];
    int b = blockIdx.x, t = threadIdx.x;
    h[t] = 0;
    __syncthreads();
    int p0 = boffs[b], p1 = boffs[b + 1];
    for (int p = p0 + t; p < p1; p += 256)
        atomicAdd(&h[pairs[p] >> 24], 1);
    __syncthreads();
    int myh = h[t];
    sh[t] = myh;
    __syncthreads();
    #pragma unroll
    for (int d = 1; d < 256; d <<= 1) {
        int val = (t >= d) ? sh[t - d] : 0;
        __syncthreads();
        sh[t] += val;
        __syncthreads();
    }
    int excl = sh[t] - myh;
    int node = (b << BSHIFT) + t;
    if (t < BRANGE) {
        cur[t] = p0 + excl;
        if (node < N) {
            offs[node] = p0 + excl;
            dinv[node] = rsqrtf((float)(myh + 1));
        }
    }
    if (b == 0 && t == 0) offs[N] = NEDGES;
    __syncthreads();
    for (int p = p0 + t; p < p1; p += 256) {
        uint pr = pairs[p];
        int pos = atomicAdd(&cur[pr >> 24], 1);
        csr[pos] = (int)(pr & 0x00FFFFFFu);
    }
}

// ---------------- MFMA GEMM (f16): msg[n,128] = (X[n,128] @ W[128,128]) * dinv[row] ----

__global__ __launch_bounds__(256) void k_gemm_f32(const float* __restrict__ X,
                                                  const short8v* __restrict__ wf,
                                                  const float* __restrict__ dinv,
                                                  ushort* __restrict__ Y, int nrows) {
    __shared__ short8v sW[2048];
    const int tid = threadIdx.x;
    const int lane = tid & 63;
    const int w = tid >> 6;

    for (int s = tid; s < 2048; s += 256) sW[s] = wf[s];
    __syncthreads();

    const int row0 = blockIdx.x * 64 + w * 16;
    const int arow = row0 + (lane & 15);
    float4v acc[8];
    #pragma unroll
    for (int ct = 0; ct < 8; ++ct) acc[ct] = (float4v)0.f;

    #pragma unroll
    for (int kk = 0; kk < 4; ++kk) {
        short8v a = (short8v)0;
        if (arow < nrows) {
            const float* xp = X + (size_t)arow * 128 + kk * 32 + ((lane >> 4) * 8);
            float4 f0 = ((const float4*)xp)[0];
            float4 f1 = ((const float4*)xp)[1];
            a[0] = f2h_s(f0.x); a[1] = f2h_s(f0.y);
            a[2] = f2h_s(f0.z); a[3] = f2h_s(f0.w);
            a[4] = f2h_s(f1.x); a[5] = f2h_s(f1.y);
            a[6] = f2h_s(f1.z); a[7] = f2h_s(f1.w);
        }
        #pragma unroll
        for (int ct = 0; ct < 8; ++ct)
            acc[ct] = __builtin_amdgcn_mfma_f32_16x16x32_f16(a, sW[(kk * 8 + ct) * 64 + lane],
                                                             acc[ct], 0, 0, 0);
    }

    const int orow = row0 + ((lane >> 4) << 2);
    #pragma unroll
    for (int r = 0; r < 4; ++r) {
        int row = orow + r;
        if (row < nrows) {
            float dr = dinv[row];
            #pragma unroll
            for (int ct = 0; ct < 8; ++ct)
                Y[(size_t)row * 128 + ct * 16 + (lane & 15)] = f2h_u(acc[ct][r] * dr);
        }
    }
}

// fp16-input variant (layer 2): A fragments load directly
__global__ __launch_bounds__(256) void k_gemm_h16(const ushort* __restrict__ X,
                                                  const short8v* __restrict__ wf,
                                                  const float* __restrict__ dinv,
                                                  ushort* __restrict__ Y, int nrows) {
    __shared__ short8v sW[2048];
    const int tid = threadIdx.x;
    const int lane = tid & 63;
    const int w = tid >> 6;

    for (int s = tid; s < 2048; s += 256) sW[s] = wf[s];
    __syncthreads();

    const int row0 = blockIdx.x * 64 + w * 16;
    const int arow = row0 + (lane & 15);
    float4v acc[8];
    #pragma unroll
    for (int ct = 0; ct < 8; ++ct) acc[ct] = (float4v)0.f;

    #pragma unroll
    for (int kk = 0; kk < 4; ++kk) {
        short8v a = (short8v)0;
        if (arow < nrows)
            a = *(const short8v*)(X + (size_t)arow * 128 + kk * 32 + ((lane >> 4) * 8));
        #pragma unroll
        for (int ct = 0; ct < 8; ++ct)
            acc[ct] = __builtin_amdgcn_mfma_f32_16x16x32_f16(a, sW[(kk * 8 + ct) * 64 + lane],
                                                             acc[ct], 0, 0, 0);
    }

    const int orow = row0 + ((lane >> 4) << 2);
    #pragma unroll
    for (int r = 0; r < 4; ++r) {
        int row = orow + r;
        if (row < nrows) {
            float dr = dinv[row];
            #pragma unroll
            for (int ct = 0; ct < 8; ++ct)
                Y[(size_t)row * 128 + ct * 16 + (lane & 15)] = f2h_u(acc[ct][r] * dr);
        }
    }
}

// ---------------- CSR aggregation: wave/node, fp16 packed adds, masked 6-deep ----------------

__global__ __launch_bounds__(256) void k_agg(const uint* __restrict__ msg,
                                             const float* __restrict__ dinv,
                                             const int* __restrict__ offs,
                                             const int* __restrict__ csr,
                                             const float* __restrict__ bias,
                                             uint* __restrict__ outb, int n, int dorelu) {
    int wid = (int)((blockIdx.x * 256 + threadIdx.x) >> 6);
    if (wid >= n) return;
    const int lane = threadIdx.x & 63;
    __half2 a0 = u2h2(msg[(size_t)wid * 64 + lane]);  // self contribution
    __half2 a1 = u2h2(0u), a2 = u2h2(0u);
    const int e0 = offs[wid], e1 = offs[wid + 1];
    for (int e = e0; e < e1; e += 64) {
        int me = e + lane;
        int sidx = (me < e1) ? csr[me] : 0;
        int cnt = min(64, e1 - e);
        for (int kb = 0; kb < cnt; kb += 6) {
            int lim = cnt - 1;
            int s0 = __shfl(sidx, min(kb + 0, lim));
            int s1 = __shfl(sidx, min(kb + 1, lim));
            int s2 = __shfl(sidx, min(kb + 2, lim));
            int s3 = __shfl(sidx, min(kb + 3, lim));
            int s4 = __shfl(sidx, min(kb + 4, lim));
            int s5 = __shfl(sidx, min(kb + 5, lim));
            uint u0 = msg[(size_t)s0 * 64 + lane];
            uint u1 = msg[(size_t)s1 * 64 + lane];
            uint u2 = msg[(size_t)s2 * 64 + lane];
            uint u3 = msg[(size_t)s3 * 64 + lane];
            uint u4 = msg[(size_t)s4 * 64 + lane];
            uint u5 = msg[(size_t)s5 * 64 + lane];
            u1 = (kb + 1 < cnt) ? u1 : 0u;
            u2 = (kb + 2 < cnt) ? u2 : 0u;
            u3 = (kb + 3 < cnt) ? u3 : 0u;
            u4 = (kb + 4 < cnt) ? u4 : 0u;
            u5 = (kb + 5 < cnt) ? u5 : 0u;
            a0 = __hadd2(a0, u2h2(u0));
            a1 = __hadd2(a1, u2h2(u1));
            a2 = __hadd2(a2, u2h2(u2));
            a0 = __hadd2(a0, u2h2(u3));
            a1 = __hadd2(a1, u2h2(u4));
            a2 = __hadd2(a2, u2h2(u5));
        }
    }
    __half2 acc = __hadd2(__hadd2(a0, a1), a2);
    float2 f = __half22float2(acc);
    float dd = dinv[wid];
    float ax = f.x * dd, ay = f.y * dd;
    if (bias) {
        ax += bias[lane * 2];
        ay += bias[lane * 2 + 1];
        if (dorelu) { ax = fmaxf(ax, 0.f); ay = fmaxf(ay, 0.f); }
    }
    outb[(size_t)wid * 64 + lane] = h22u(__floats2half2_rn(ax, ay));
}

// ---------------- pooling: (64 x 32) blocks, uint4 loads, NON-ATOMIC partial sums ----------------

__global__ __launch_bounds__(256) void k_pool(const uint4* __restrict__ buf,
                                              const int* __restrict__ gstart,
                                              const int* __restrict__ gend,
                                              float* __restrict__ partial) {
    __shared__ float red[256][8];
    int g = blockIdx.x, chunk = blockIdx.y;
    int t = threadIdx.x;
    int s = gstart[g], e = gend[g];
    int per = (e - s + POOLCH - 1) / POOLCH;
    int r0 = s + chunk * per, r1 = min(e, r0 + per);
    int q = t & 15;      // row quarter (uint4 index; 8 channels)
    int ri = t >> 4;     // row offset 0..15
    float acc[8] = {0.f, 0.f, 0.f, 0.f, 0.f, 0.f, 0.f, 0.f};
    for (int r = r0 + ri; r < r1; r += 16) {
        uint4 u = buf[(size_t)r * 16 + q];
        float2 f0 = __half22float2(u2h2(u.x));
        float2 f1 = __half22float2(u2h2(u.y));
        float2 f2 = __half22float2(u2h2(u.z));
        float2 f3 = __half22float2(u2h2(u.w));
        acc[0] += f0.x; acc[1] += f0.y;
        acc[2] += f1.x; acc[3] += f1.y;
        acc[4] += f2.x; acc[5] += f2.y;
        acc[6] += f3.x; acc[7] += f3.y;
    }
    #pragma unroll
    for (int j = 0; j < 8; ++j) red[t][j] = acc[j];
    __syncthreads();
    if (t < 128) {       // t = q2*8 + j handles channel q2*8+j
        int q2 = t >> 3, j = t & 7;
        float v = 0.f;
        #pragma unroll
        for (int i = 0; i < 16; ++i) v += red[i * 16 + q2][j];
        partial[((size_t)g * POOLCH + chunk) * 128 + (q2 << 3) + j] = v;
    }
}

// ---------------- final: reduce partials + linear head (one block per graph) ----------------

__global__ __launch_bounds__(128) void k_final(const float* __restrict__ partial,
                                               const int* __restrict__ gstart,
                                               const int* __restrict__ gend,
                                               const float* __restrict__ b2,
                                               const float* __restrict__ linW,
                                               const float* __restrict__ linb,
                                               float* __restrict__ out) {
    __shared__ float red[128][8];
    int g = blockIdx.x, t = threadIdx.x;  // t = channel c
    float v = 0.f;
    #pragma unroll 8
    for (int ch = 0; ch < POOLCH; ++ch)
        v += partial[((size_t)g * POOLCH + ch) * 128 + t];
    float cnt = (float)(gend[g] - gstart[g]);
    float sv = v / fmaxf(cnt, 1.0f) + b2[t];
    #pragma unroll
    for (int k = 0; k < 8; ++k) red[t][k] = sv * linW[(size_t)t * 8 + k];
    __syncthreads();
    #pragma unroll
    for (int st = 64; st > 0; st >>= 1) {
        if (t < st) {
            #pragma unroll
            for (int k = 0; k < 8; ++k) red[t][k] += red[t + st][k];
        }
        __syncthreads();
    }
    if (t < 8) out[(size_t)g * 8 + t] = red[0][t] + linb[t];
}

// ---------------- launch ----------------

extern "C" void kernel_launch(void* const* d_in, const int* in_sizes, int n_in,
                              void* d_out, int out_size, void* d_ws, size_t ws_size,
                              hipStream_t stream) {
    const float* x     = (const float*)d_in[0];
    const int*   ei    = (const int*)d_in[1];  // [2,E]: src = ei, dst = ei+E
    const int*   batch = (const int*)d_in[2];
    const float* W1    = (const float*)d_in[3];
    const float* b1    = (const float*)d_in[4];
    const float* W2    = (const float*)d_in[5];
    const float* b2    = (const float*)d_in[6];
    const float* linW  = (const float*)d_in[7];
    const float* linb  = (const float*)d_in[8];
    float* out = (float*)d_out;

    const int N = NNODES, E = NEDGES;
    const int* src = ei;
    const int* dst = ei + E;

    char* ws = (char*)d_ws;
    uint*  bufA16 = (uint*)ws;     ws += (size_t)N * 64 * 4;   // msg (fp16), 25.6MB
    uint*  bufH16 = (uint*)ws;     ws += (size_t)N * 64 * 4;   // h (fp16), 25.6MB
    float* dinv   = (float*)ws;    ws += (size_t)N * 4;
    int*   offs   = (int*)ws;      ws += (size_t)(N + 1) * 4;
    int*   csr    = (int*)ws;      ws += (size_t)E * 4;        // 6.4MB
    int*   bcnt   = (int*)ws;      ws += NB * 4;               // zero region start
    int*   done   = (int*)ws;      ws += 2 * 4;                // [0]=bcount ticket
    int*   boffs  = (int*)ws;      ws += (NB + 1) * 4;
    int*   bcur   = (int*)ws;      ws += NB * 4;
    int*   gstart = (int*)ws;      ws += NGRAPHS * 4;
    int*   gend   = (int*)ws;      ws += NGRAPHS * 4;
    short8v* wf1  = (short8v*)ws;  ws += 2048 * 16;            // fragment-ordered W1 (32KB)
    short8v* wf2  = (short8v*)ws;  ws += 2048 * 16;            // fragment-ordered W2 (32KB)
    float* partial= (float*)ws;    ws += (size_t)NGRAPHS * POOLCH * 128 * 4;  // 1MB
    // pairs aliases bufH16: CSR build completes before agg1 writes h1
    uint*  pairs  = (uint*)bufH16;  // 6.4MB < 25.6MB

    const int B = 256;

    // setup: zero(4) + prepw(2) + bounds(391) = 397 blocks
    k_setup<<<397, B, 0, stream>>>(bcnt, W1, W2, wf1, wf2, batch, gstart, gend);

    // CSR build
    k_bcount_scan<<<256, B, 0, stream>>>(dst, bcnt, boffs, bcur, &done[0], E);
    k_bscatter<<<(E + 2047) / 2048, B, 0, stream>>>(src, dst, bcur, pairs, E);
    k_build<<<NB, B, 0, stream>>>(pairs, boffs, offs, dinv, csr, N);

    const int gemmGrid = (N + 63) / 64;
    const int aggGrid = (N * 64 + B - 1) / B;

    // layer 1
    k_gemm_f32<<<gemmGrid, B, 0, stream>>>(x, wf1, dinv, (ushort*)bufA16, N);
    k_agg<<<aggGrid, B, 0, stream>>>(bufA16, dinv, offs, csr, b1, bufH16, N, 1);

    // layer 2
    k_gemm_h16<<<gemmGrid, B, 0, stream>>>((const ushort*)bufH16, wf2, dinv,
                                           (ushort*)bufA16, N);
    k_agg<<<aggGrid, B, 0, stream>>>(bufA16, dinv, offs, csr, nullptr, bufH16, N, 0);

    // pool (non-atomic partials) + head
    k_pool<<<dim3(NGRAPHS, POOLCH), B, 0, stream>>>((const uint4*)bufH16, gstart, gend, partial);
    k_final<<<NGRAPHS, 128, 0, stream>>>(partial, gstart, gend, b2, linW, linb, out);
}

// Round 14
// 221.091 us; speedup vs baseline: 1.1388x; 1.1388x over previous
//
#include <hip/hip_runtime.h>
#include <hip/hip_fp16.h>
#include <cstdint>
#include <cstddef>

#define NNODES 100000
#define NEDGES 1600000
#define NGRAPHS 64
#define BSHIFT 7
#define BRANGE 128
#define NB 782   // ceil(NNODES / 128)
#define CAP 4096 // edges per bucket frame (mean 2046, sd 45 -> >40 sigma headroom)
#define NZ NB    // ints to zero (bcur)

typedef short short8v __attribute__((ext_vector_type(8)));
typedef float float4v __attribute__((ext_vector_type(4)));

__device__ inline short f2h_s(float f) {
    __half h = __float2half(f);
    return __builtin_bit_cast(short, h);
}
__device__ inline ushort f2h_u(float f) {
    __half h = __float2half(f);
    return __builtin_bit_cast(ushort, h);
}
__device__ inline __half2 u2h2(uint u) { return __builtin_bit_cast(__half2, u); }
__device__ inline uint h22u(__half2 h) { return __builtin_bit_cast(uint, h); }

// ---------------- setup: zero ∪ prepw ∪ bounds (block-range partitioned) ----------------
// blocks 0..3: zero bcur. blocks 4,5: W1/W2 -> fragment-ordered fp16. blocks 6..396: bounds.

__global__ __launch_bounds__(256) void k_setup(int* __restrict__ zb,
                                               const float* __restrict__ W1,
                                               const float* __restrict__ W2,
                                               short8v* __restrict__ o1,
                                               short8v* __restrict__ o2,
                                               const int* __restrict__ batch,
                                               int* __restrict__ gstart,
                                               int* __restrict__ gend) {
    int b = blockIdx.x, t = threadIdx.x;
    if (b < 4) {
        int i = b * 256 + t;
        if (i < NZ) zb[i] = 0;
    } else if (b < 6) {
        const float* W = (b == 5) ? W2 : W1;
        short8v* o = (b == 5) ? o2 : o1;
        for (int s = t; s < 2048; s += 256) {
            int p = s >> 6, l = s & 63;
            int kb = (p >> 3) * 32 + ((l >> 4) * 8);
            int j = (p & 7) * 16 + (l & 15);
            short8v v;
            #pragma unroll
            for (int i = 0; i < 8; ++i)
                v[i] = f2h_s(W[(size_t)(kb + i) * 128 + j]);
            o[s] = v;
        }
    } else {
        int i = (b - 6) * 256 + t;
        if (i < NNODES) {
            int bb = batch[i];
            if (i == 0 || batch[i - 1] != bb) gstart[bb] = i;
            if (i == NNODES - 1 || batch[i + 1] != bb) gend[bb] = i + 1;
        }
    }
}

// ---------------- P1: bucket scatter with direct atomic reservation (no pre-count) ----------------
// pairs frame for bucket b is [b*CAP, b*CAP + CAP); bcur[b] ends up as the bucket count.

#define P1_EPT 8
__global__ __launch_bounds__(256) void k_bscatter(const int* __restrict__ src,
                                                  const int* __restrict__ dst,
                                                  int* __restrict__ bcur,
                                                  uint* __restrict__ pairs, int E) {
    __shared__ int h[NB];
    __shared__ int base[NB];
    int t = threadIdx.x;
    long long c0 = (long long)blockIdx.x * 2048;
    if (c0 >= E) return;
    for (int i = t; i < NB; i += 256) h[i] = 0;
    __syncthreads();
    int myb[P1_EPT], mylp[P1_EPT];
    uint myv[P1_EPT];
    #pragma unroll
    for (int k = 0; k < P1_EPT; ++k) {
        long long e = c0 + t + k * 256;
        if (e < E) {
            int d = dst[e];
            myv[k] = (uint)src[e] | ((uint)(d & (BRANGE - 1)) << 24);
            myb[k] = d >> BSHIFT;
            mylp[k] = atomicAdd(&h[myb[k]], 1);
        } else myb[k] = -1;
    }
    __syncthreads();
    for (int i = t; i < NB; i += 256)
        base[i] = h[i] ? atomicAdd(&bcur[i], h[i]) : 0;
    __syncthreads();
    #pragma unroll
    for (int k = 0; k < P1_EPT; ++k)
        if (myb[k] >= 0) {
            int pos = base[myb[k]] + mylp[k];
            if (pos < CAP)  // statistically unreachable; safety clamp
                pairs[(size_t)myb[k] * CAP + pos] = myv[k];
        }
}

// ---------------- fused per-bucket: histogram -> dinv + node ranges -> CSR scatter ----------------

__global__ __launch_bounds__(256) void k_build(const uint* __restrict__ pairs,
                                               const int* __restrict__ bcur,
                                               int2* __restrict__ nr,
                                               float* __restrict__ dinv,
                                               int* __restrict__ csr, int N) {
    __shared__ int h[256];
    __shared__ int sh[256];
    __shared__ int cur[BRANGE];
    int b = blockIdx.x, t = threadIdx.x;
    h[t] = 0;
    __syncthreads();
    const int p0 = b * CAP;
    const int cntb = min(bcur[b], CAP);
    for (int p = t; p < cntb; p += 256)
        atomicAdd(&h[pairs[p0 + p] >> 24], 1);
    __syncthreads();
    int myh = h[t];
    sh[t] = myh;
    __syncthreads();
    #pragma unroll
    for (int d = 1; d < 256; d <<= 1) {
        int val = (t >= d) ? sh[t - d] : 0;
        __syncthreads();
        sh[t] += val;
        __syncthreads();
    }
    int excl = sh[t] - myh;
    int node = (b << BSHIFT) + t;
    if (t < BRANGE) {
        cur[t] = p0 + excl;
        if (node < N) {
            nr[node] = make_int2(p0 + excl, p0 + excl + myh);
            dinv[node] = rsqrtf((float)(myh + 1));
        }
    }
    __syncthreads();
    for (int p = t; p < cntb; p += 256) {
        uint pr = pairs[p0 + p];
        int pos = atomicAdd(&cur[pr >> 24], 1);
        csr[pos] = (int)(pr & 0x00FFFFFFu);
    }
}

// ---------------- MFMA GEMM (f16): msg[n,128] = (X[n,128] @ W[128,128]) * dinv[row] ----

__global__ __launch_bounds__(256) void k_gemm_f32(const float* __restrict__ X,
                                                  const short8v* __restrict__ wf,
                                                  const float* __restrict__ dinv,
                                                  ushort* __restrict__ Y, int nrows) {
    __shared__ short8v sW[2048];
    const int tid = threadIdx.x;
    const int lane = tid & 63;
    const int w = tid >> 6;

    for (int s = tid; s < 2048; s += 256) sW[s] = wf[s];
    __syncthreads();

    const int row0 = blockIdx.x * 64 + w * 16;
    const int arow = row0 + (lane & 15);
    float4v acc[8];
    #pragma unroll
    for (int ct = 0; ct < 8; ++ct) acc[ct] = (float4v)0.f;

    #pragma unroll
    for (int kk = 0; kk < 4; ++kk) {
        short8v a = (short8v)0;
        if (arow < nrows) {
            const float* xp = X + (size_t)arow * 128 + kk * 32 + ((lane >> 4) * 8);
            float4 f0 = ((const float4*)xp)[0];
            float4 f1 = ((const float4*)xp)[1];
            a[0] = f2h_s(f0.x); a[1] = f2h_s(f0.y);
            a[2] = f2h_s(f0.z); a[3] = f2h_s(f0.w);
            a[4] = f2h_s(f1.x); a[5] = f2h_s(f1.y);
            a[6] = f2h_s(f1.z); a[7] = f2h_s(f1.w);
        }
        #pragma unroll
        for (int ct = 0; ct < 8; ++ct)
            acc[ct] = __builtin_amdgcn_mfma_f32_16x16x32_f16(a, sW[(kk * 8 + ct) * 64 + lane],
                                                             acc[ct], 0, 0, 0);
    }

    const int orow = row0 + ((lane >> 4) << 2);
    #pragma unroll
    for (int r = 0; r < 4; ++r) {
        int row = orow + r;
        if (row < nrows) {
            float dr = dinv[row];
            #pragma unroll
            for (int ct = 0; ct < 8; ++ct)
                Y[(size_t)row * 128 + ct * 16 + (lane & 15)] = f2h_u(acc[ct][r] * dr);
        }
    }
}

// fp16-input variant (layer 2): A fragments load directly
__global__ __launch_bounds__(256) void k_gemm_h16(const ushort* __restrict__ X,
                                                  const short8v* __restrict__ wf,
                                                  const float* __restrict__ dinv,
                                                  ushort* __restrict__ Y, int nrows) {
    __shared__ short8v sW[2048];
    const int tid = threadIdx.x;
    const int lane = tid & 63;
    const int w = tid >> 6;

    for (int s = tid; s < 2048; s += 256) sW[s] = wf[s];
    __syncthreads();

    const int row0 = blockIdx.x * 64 + w * 16;
    const int arow = row0 + (lane & 15);
    float4v acc[8];
    #pragma unroll
    for (int ct = 0; ct < 8; ++ct) acc[ct] = (float4v)0.f;

    #pragma unroll
    for (int kk = 0; kk < 4; ++kk) {
        short8v a = (short8v)0;
        if (arow < nrows)
            a = *(const short8v*)(X + (size_t)arow * 128 + kk * 32 + ((lane >> 4) * 8));
        #pragma unroll
        for (int ct = 0; ct < 8; ++ct)
            acc[ct] = __builtin_amdgcn_mfma_f32_16x16x32_f16(a, sW[(kk * 8 + ct) * 64 + lane],
                                                             acc[ct], 0, 0, 0);
    }

    const int orow = row0 + ((lane >> 4) << 2);
    #pragma unroll
    for (int r = 0; r < 4; ++r) {
        int row = orow + r;
        if (row < nrows) {
            float dr = dinv[row];
            #pragma unroll
            for (int ct = 0; ct < 8; ++ct)
                Y[(size_t)row * 128 + ct * 16 + (lane & 15)] = f2h_u(acc[ct][r] * dr);
        }
    }
}

// ---------------- CSR aggregation: wave/node, fp16 packed adds, masked 6-deep ----------------
// h[i,:] = relu( dinv[i] * (msg[i,:] + sum_{s in in(i)} msg[s,:]) + bias )

__global__ __launch_bounds__(256) void k_agg(const uint* __restrict__ msg,
                                             const float* __restrict__ dinv,
                                             const int2* __restrict__ nr,
                                             const int* __restrict__ csr,
                                             const float* __restrict__ bias,
                                             uint* __restrict__ outb, int n, int dorelu) {
    int wid = (int)((blockIdx.x * 256 + threadIdx.x) >> 6);
    if (wid >= n) return;
    const int lane = threadIdx.x & 63;
    __half2 a0 = u2h2(msg[(size_t)wid * 64 + lane]);  // self contribution
    __half2 a1 = u2h2(0u), a2 = u2h2(0u);
    const int2 rg = nr[wid];
    const int e0 = rg.x, e1 = rg.y;
    for (int e = e0; e < e1; e += 64) {
        int me = e + lane;
        int sidx = (me < e1) ? csr[me] : 0;
        int cnt = min(64, e1 - e);
        for (int kb = 0; kb < cnt; kb += 6) {
            int lim = cnt - 1;
            int s0 = __shfl(sidx, min(kb + 0, lim));
            int s1 = __shfl(sidx, min(kb + 1, lim));
            int s2 = __shfl(sidx, min(kb + 2, lim));
            int s3 = __shfl(sidx, min(kb + 3, lim));
            int s4 = __shfl(sidx, min(kb + 4, lim));
            int s5 = __shfl(sidx, min(kb + 5, lim));
            uint u0 = msg[(size_t)s0 * 64 + lane];
            uint u1 = msg[(size_t)s1 * 64 + lane];
            uint u2 = msg[(size_t)s2 * 64 + lane];
            uint u3 = msg[(size_t)s3 * 64 + lane];
            uint u4 = msg[(size_t)s4 * 64 + lane];
            uint u5 = msg[(size_t)s5 * 64 + lane];
            u1 = (kb + 1 < cnt) ? u1 : 0u;
            u2 = (kb + 2 < cnt) ? u2 : 0u;
            u3 = (kb + 3 < cnt) ? u3 : 0u;
            u4 = (kb + 4 < cnt) ? u4 : 0u;
            u5 = (kb + 5 < cnt) ? u5 : 0u;
            a0 = __hadd2(a0, u2h2(u0));
            a1 = __hadd2(a1, u2h2(u1));
            a2 = __hadd2(a2, u2h2(u2));
            a0 = __hadd2(a0, u2h2(u3));
            a1 = __hadd2(a1, u2h2(u4));
            a2 = __hadd2(a2, u2h2(u5));
        }
    }
    __half2 acc = __hadd2(__hadd2(a0, a1), a2);
    float2 f = __half22float2(acc);
    float dd = dinv[wid];
    float ax = f.x * dd, ay = f.y * dd;
    if (bias) {
        ax += bias[lane * 2];
        ay += bias[lane * 2 + 1];
        if (dorelu) { ax = fmaxf(ax, 0.f); ay = fmaxf(ay, 0.f); }
    }
    outb[(size_t)wid * 64 + lane] = h22u(__floats2half2_rn(ax, ay));
}

// ---------------- pooling: (64 x 32) blocks, uint4 loads, non-atomic partial sums ----------------

#define POOLCH 32

__global__ __launch_bounds__(256) void k_pool(const uint4* __restrict__ buf,
                                              const int* __restrict__ gstart,
                                              const int* __restrict__ gend,
                                              float* __restrict__ partial) {
    __shared__ float red[256][8];
    int g = blockIdx.x, chunk = blockIdx.y;
    int t = threadIdx.x;
    int s = gstart[g], e = gend[g];
    int per = (e - s + POOLCH - 1) / POOLCH;
    int r0 = s + chunk * per, r1 = min(e, r0 + per);
    int q = t & 15;
    int ri = t >> 4;
    float acc[8] = {0.f, 0.f, 0.f, 0.f, 0.f, 0.f, 0.f, 0.f};
    for (int r = r0 + ri; r < r1; r += 16) {
        uint4 u = buf[(size_t)r * 16 + q];
        float2 f0 = __half22float2(u2h2(u.x));
        float2 f1 = __half22float2(u2h2(u.y));
        float2 f2 = __half22float2(u2h2(u.z));
        float2 f3 = __half22float2(u2h2(u.w));
        acc[0] += f0.x; acc[1] += f0.y;
        acc[2] += f1.x; acc[3] += f1.y;
        acc[4] += f2.x; acc[5] += f2.y;
        acc[6] += f3.x; acc[7] += f3.y;
    }
    #pragma unroll
    for (int j = 0; j < 8; ++j) red[t][j] = acc[j];
    __syncthreads();
    if (t < 128) {
        int q2 = t >> 3, j = t & 7;
        float v = 0.f;
        #pragma unroll
        for (int i = 0; i < 16; ++i) v += red[i * 16 + q2][j];
        partial[((size_t)g * POOLCH + chunk) * 128 + (q2 << 3) + j] = v;
    }
}

// ---------------- final: reduce partials + linear head (one block per graph) ----------------

__global__ __launch_bounds__(128) void k_final(const float* __restrict__ partial,
                                               const int* __restrict__ gstart,
                                               const int* __restrict__ gend,
                                               const float* __restrict__ b2,
                                               const float* __restrict__ linW,
                                               const float* __restrict__ linb,
                                               float* __restrict__ out) {
    __shared__ float red[128][8];
    int g = blockIdx.x, t = threadIdx.x;  // t = channel c
    float v = 0.f;
    #pragma unroll 8
    for (int ch = 0; ch < POOLCH; ++ch)
        v += partial[((size_t)g * POOLCH + ch) * 128 + t];
    float cnt = (float)(gend[g] - gstart[g]);
    float sv = v / fmaxf(cnt, 1.0f) + b2[t];
    #pragma unroll
    for (int k = 0; k < 8; ++k) red[t][k] = sv * linW[(size_t)t * 8 + k];
    __syncthreads();
    #pragma unroll
    for (int st = 64; st > 0; st >>= 1) {
        if (t < st) {
            #pragma unroll
            for (int k = 0; k < 8; ++k) red[t][k] += red[t + st][k];
        }
        __syncthreads();
    }
    if (t < 8) out[(size_t)g * 8 + t] = red[0][t] + linb[t];
}

// ---------------- launch ----------------

extern "C" void kernel_launch(void* const* d_in, const int* in_sizes, int n_in,
                              void* d_out, int out_size, void* d_ws, size_t ws_size,
                              hipStream_t stream) {
    const float* x     = (const float*)d_in[0];
    const int*   ei    = (const int*)d_in[1];  // [2,E]: src = ei, dst = ei+E
    const int*   batch = (const int*)d_in[2];
    const float* W1    = (const float*)d_in[3];
    const float* b1    = (const float*)d_in[4];
    const float* W2    = (const float*)d_in[5];
    const float* b2    = (const float*)d_in[6];
    const float* linW  = (const float*)d_in[7];
    const float* linb  = (const float*)d_in[8];
    float* out = (float*)d_out;

    const int N = NNODES, E = NEDGES;
    const int* src = ei;
    const int* dst = ei + E;

    char* ws = (char*)d_ws;
    uint*  bufA16 = (uint*)ws;     ws += (size_t)N * 64 * 4;   // msg (fp16), 25.6MB
    uint*  bufH16 = (uint*)ws;     ws += (size_t)N * 64 * 4;   // h (fp16), 25.6MB
    float* dinv   = (float*)ws;    ws += (size_t)N * 4;
    int2*  nr     = (int2*)ws;     ws += (size_t)N * 8;        // per-node (start,end)
    int*   csr    = (int*)ws;      ws += (size_t)NB * CAP * 4; // 12.8MB bucket frames
    int*   bcur   = (int*)ws;      ws += NB * 4;               // zero region
    int*   gstart = (int*)ws;      ws += NGRAPHS * 4;
    int*   gend   = (int*)ws;      ws += NGRAPHS * 4;
    short8v* wf1  = (short8v*)ws;  ws += 2048 * 16;            // fragment-ordered W1 (32KB)
    short8v* wf2  = (short8v*)ws;  ws += 2048 * 16;            // fragment-ordered W2 (32KB)
    float* partial= (float*)ws;    ws += (size_t)NGRAPHS * POOLCH * 128 * 4;  // 1MB
    // pairs aliases bufH16 (12.8MB < 25.6MB): CSR build completes before agg1 writes h1
    uint*  pairs  = (uint*)bufH16;

    const int B = 256;

    // setup: zero(4) + prepw(2) + bounds(391) = 397 blocks
    k_setup<<<397, B, 0, stream>>>(bcur, W1, W2, wf1, wf2, batch, gstart, gend);

    // CSR build (2 kernels: scatter with direct reservation, then per-bucket build)
    k_bscatter<<<(E + 2047) / 2048, B, 0, stream>>>(src, dst, bcur, pairs, E);
    k_build<<<NB, B, 0, stream>>>(pairs, bcur, nr, dinv, csr, N);

    const int gemmGrid = (N + 63) / 64;
    const int aggGrid = (N * 64 + B - 1) / B;

    // layer 1
    k_gemm_f32<<<gemmGrid, B, 0, stream>>>(x, wf1, dinv, (ushort*)bufA16, N);
    k_agg<<<aggGrid, B, 0, stream>>>(bufA16, dinv, nr, csr, b1, bufH16, N, 1);

    // layer 2
    k_gemm_h16<<<gemmGrid, B, 0, stream>>>((const ushort*)bufH16, wf2, dinv,
                                           (ushort*)bufA16, N);
    k_agg<<<aggGrid, B, 0, stream>>>(bufA16, dinv, nr, csr, nullptr, bufH16, N, 0);

    // pool (non-atomic partials) + head
    k_pool<<<dim3(NGRAPHS, POOLCH), B, 0, stream>>>((const uint4*)bufH16, gstart, gend, partial);
    k_final<<<NGRAPHS, 128, 0, stream>>>(partial, gstart, gend, b2, linW, linb, out);
}